// Round 5
// baseline (447.511 us; speedup 1.0000x reference)
//
#include <hip/hip_runtime.h>
#include <cstdint>

constexpr int NCOLS   = 4096;
constexpr int THREADS = 256;
constexpr int WPB     = 4;      // waves per block; 1 wave = 1 row
constexpr int CAP     = 256;    // per-wave candidate capacity

typedef float floatx4 __attribute__((ext_vector_type(4)));

__device__ __forceinline__ uint32_t mbcnt64(uint64_t m) {
    uint32_t c = __builtin_amdgcn_mbcnt_lo((uint32_t)m, 0u);
    return __builtin_amdgcn_mbcnt_hi((uint32_t)(m >> 32), c);
}

__global__ __launch_bounds__(THREADS) void topk_sparsify(
    const float* __restrict__ X, float* __restrict__ out)
{
    const int wave = threadIdx.x >> 6;
    const int lane = threadIdx.x & 63;
    const int row  = blockIdx.x * WPB + wave;

    // Per-wave private candidate segment — no cross-wave sharing, no barriers.
    __shared__ uint32_t cand[WPB * CAP];
    uint32_t* __restrict__ wc = cand + wave * CAP;

    const floatx4* __restrict__ x4 =
        reinterpret_cast<const floatx4*>(X + (size_t)row * NCOLS);
    floatx4* __restrict__ o4 = reinterpret_cast<floatx4*>(out + (size_t)row * NCOLS);

    // ---- whole row in registers: 16 float4 per lane (64 floats)
    floatx4 v[16];
#pragma unroll
    for (int i = 0; i < 16; ++i) v[i] = x4[lane + 64 * i];

    // ---- sigma from sum of squares (wave-local shuffle reduce)
    float s0 = 0, s1 = 0, s2 = 0, s3 = 0;
#pragma unroll
    for (int i = 0; i < 16; ++i) {
        s0 = fmaf(v[i].x, v[i].x, s0);
        s1 = fmaf(v[i].y, v[i].y, s1);
        s2 = fmaf(v[i].z, v[i].z, s2);
        s3 = fmaf(v[i].w, v[i].w, s3);
    }
    float ss = (s0 + s1) + (s2 + s3);
#pragma unroll
    for (int off = 32; off >= 1; off >>= 1) ss += __shfl_xor(ss, off, 64);
    const float sigma = sqrtf(ss) * (1.0f / 64.0f);   // sqrt(ss/4096)

    // ---- find T with 65 <= C <= CAP (ballot counts; abs is a free src modifier)
    float T = 2.12f * sigma;
    uint32_t tb = 0, C = 0;
    bool ok = false;
    for (int it = 0; it < 12; ++it) {
        uint32_t c = 0;
#pragma unroll
        for (int i = 0; i < 16; ++i) {
            c += (uint32_t)__popcll(__ballot(__builtin_fabsf(v[i].x) > T));
            c += (uint32_t)__popcll(__ballot(__builtin_fabsf(v[i].y) > T));
            c += (uint32_t)__popcll(__ballot(__builtin_fabsf(v[i].z) > T));
            c += (uint32_t)__popcll(__ballot(__builtin_fabsf(v[i].w) > T));
        }
        C = c;                                  // wave-uniform
        if (C >= 65u && C <= (uint32_t)CAP) { tb = __float_as_uint(T); ok = true; break; }
        T = (C < 65u) ? T * 0.82f : T * 1.25f;
    }

    uint32_t b65, Ct, M;
    if (ok) {
        // ---- gather raw bits of candidates (mbcnt compaction, wave-local)
        uint32_t base = 0;
#pragma unroll
        for (int i = 0; i < 16; ++i) {
#pragma unroll
            for (int j = 0; j < 4; ++j) {
                const float f = v[i][j];
                const bool  g = __builtin_fabsf(f) > T;
                uint64_t m = __ballot(g);
                if (g) wc[base + mbcnt64(m)] = __float_as_uint(f);
                base += (uint32_t)__popcll(m);
            }
        }

        // ---- all candidates into 4 regs/lane; strip sign on readback (4 v_and)
        uint32_t r0 = (lane       < (int)C) ? (wc[lane      ] & 0x7FFFFFFFu) : 0u;
        uint32_t r1 = (lane + 64  < (int)C) ? (wc[lane +  64] & 0x7FFFFFFFu) : 0u;
        uint32_t r2 = (lane + 128 < (int)C) ? (wc[lane + 128] & 0x7FFFFFFFu) : 0u;
        uint32_t r3 = (lane + 192 < (int)C) ? (wc[lane + 192] & 0x7FFFFFFFu) : 0u;

        uint32_t mx = max(max(r0, r1), max(r2, r3));
#pragma unroll
        for (int off = 32; off >= 1; off >>= 1)
            mx = max(mx, (uint32_t)__shfl_xor(mx, off, 64));

        // smallest m with count(> m) < 65 == 65th-largest |x| bit pattern.
        // All elements > mid (mid >= tb) are candidates, so counting is exact.
        uint32_t lo = tb + 1u, hi = mx;
        while (lo < hi) {
            uint32_t mid = lo + ((hi - lo) >> 1);
            uint32_t c = (uint32_t)(__popcll(__ballot(r0 > mid)) +
                                    __popcll(__ballot(r1 > mid)) +
                                    __popcll(__ballot(r2 > mid)) +
                                    __popcll(__ballot(r3 > mid)));
            if (c < 65u) hi = mid; else lo = mid + 1u;
        }
        b65 = lo;

        // ---- v64 = min of elements strictly > b65 (iff exactly 64 exist)
        Ct = (uint32_t)(__popcll(__ballot(r0 > b65)) +
                        __popcll(__ballot(r1 > b65)) +
                        __popcll(__ballot(r2 > b65)) +
                        __popcll(__ballot(r3 > b65)));
        uint32_t mn = 0xFFFFFFFFu;
        mn = min(mn, (r0 > b65) ? r0 : 0xFFFFFFFFu);
        mn = min(mn, (r1 > b65) ? r1 : 0xFFFFFFFFu);
        mn = min(mn, (r2 > b65) ? r2 : 0xFFFFFFFFu);
        mn = min(mn, (r3 > b65) ? r3 : 0xFFFFFFFFu);
#pragma unroll
        for (int off = 32; off >= 1; off >>= 1)
            mn = min(mn, (uint32_t)__shfl_xor(mn, off, 64));
        M = mn;
    } else {
        // ---- exact fallback: wave-local bit-pattern bisection over full row
        // (integer compares: exact under ties/denormals)
        uint32_t lo = 0u, hi = 0x7F800000u;
        while (lo < hi) {
            uint32_t mid = lo + ((hi - lo) >> 1);
            uint32_t c = 0;
#pragma unroll
            for (int i = 0; i < 16; ++i) {
#pragma unroll
                for (int j = 0; j < 4; ++j)
                    c += (uint32_t)__popcll(__ballot(
                        (__float_as_uint(v[i][j]) & 0x7FFFFFFFu) > mid));
            }
            if (c < 65u) hi = mid; else lo = mid + 1u;
        }
        b65 = lo;

        uint32_t cw = 0, mn = 0xFFFFFFFFu;
#pragma unroll
        for (int i = 0; i < 16; ++i) {
#pragma unroll
            for (int j = 0; j < 4; ++j) {
                uint32_t ab = __float_as_uint(v[i][j]) & 0x7FFFFFFFu;
                bool g = ab > b65;
                cw += (uint32_t)__popcll(__ballot(g));
                mn = min(mn, g ? ab : 0xFFFFFFFFu);
            }
        }
#pragma unroll
        for (int off = 32; off >= 1; off >>= 1)
            mn = min(mn, (uint32_t)__shfl_xor(mn, off, 64));
        Ct = cw; M = mn;
    }

    const float v65 = __uint_as_float(b65);
    const float v64 = (Ct == 64u) ? __uint_as_float(M) : v65;
    const float Q = fmaf(0.015625f, v64 - v65, v65);   // frac exact in binary

    // ---- epilogue: |x|-Q clamp + sign restore via v_bfi; nontemporal stores
#pragma unroll
    for (int i = 0; i < 16; ++i) {
        floatx4 o;
#pragma unroll
        for (int j = 0; j < 4; ++j) {
            const float f = v[i][j];
            float mag = fmaxf(__builtin_fabsf(f) - Q, 0.0f);
            o[j] = copysignf(mag, f);
        }
        __builtin_nontemporal_store(o, &o4[lane + 64 * i]);
    }
}

extern "C" void kernel_launch(void* const* d_in, const int* in_sizes, int n_in,
                              void* d_out, int out_size, void* d_ws, size_t ws_size,
                              hipStream_t stream) {
    const float* X   = (const float*)d_in[0];
    float*       out = (float*)d_out;
    const int rows = in_sizes[0] / NCOLS;   // 16384
    topk_sparsify<<<rows / WPB, THREADS, 0, stream>>>(X, out);
}